// Round 22
// baseline (167.574 us; speedup 1.0000x reference)
//
#include <hip/hip_runtime.h>
#include <math.h>

#define BIGF 3.0e38f

typedef short  s16x8 __attribute__((ext_vector_type(8)));
typedef float  f32x4 __attribute__((ext_vector_type(4)));

// bf16 helpers (manual RNE)
__device__ __forceinline__ unsigned short f2bf(float x) {
  unsigned int b = __float_as_uint(x);
  unsigned int r = b + 0x7FFFu + ((b >> 16) & 1u);
  return (unsigned short)(r >> 16);
}
__device__ __forceinline__ float bf2f(unsigned short h) {
  return __uint_as_float(((unsigned int)h) << 16);
}

// ===========================================================================
// Spatial-hash KNN (K=3), 16 lanes per query, row-range shell scan,
// cell-sorted query order, 4-deep batched point loads.
// Selection replicates the np reference's fp32 expansion distance:
//   sx  = (x*x + y*y) + z*z            (sequential, individually rounded)
//   dot = (p0 + p1) + p2, p_k = q_k*s_k
//   d2  = (sy + sx) - 2*dot
// under fp contract(off) (scan_shell-local pragma) — verified rounds 3-6.
// DO NOT TOUCH. Tie-break: lexicographic (d, idx) — scan-order independent.
// Every candidate visited exactly once. Grids G1=16/G2=10 (r21's finer
// grids regressed: boundary escalation to R=2).
// r22: GEMM is LDS-FREE (B read direct from L2-resident BT) -> no barriers,
// full occupancy, and knn2/knn1 can now ride gemm1's dispatch safely
// (r20's failure was the 33.8KB LDS reservation choking riders).
// ===========================================================================

__device__ __forceinline__ int cell_clamp(float v, int G) {
  int c = (int)(v * (float)G);
  return min(G - 1, max(0, c));
}

__device__ __forceinline__ void ins3(float d, int id,
                                     float& d0, float& d1, float& d2,
                                     int& i0, int& i1, int& i2) {
  bool l0 = (d < d0) || (d == d0 && id < i0);
  bool l1 = (d < d1) || (d == d1 && id < i1);
  bool l2 = (d < d2) || (d == d2 && id < i2);
  float nd0 = l0 ? d  : d0;  int ni0 = l0 ? id : i0;
  float nd1 = l0 ? d0 : (l1 ? d  : d1);
  int   ni1 = l0 ? i0 : (l1 ? id : i1);
  float nd2 = l1 ? d1 : (l2 ? d  : d2);
  int   ni2 = l1 ? i1 : (l2 ? id : i2);
  d0 = nd0; d1 = nd1; d2 = nd2; i0 = ni0; i1 = ni1; i2 = ni2;
}

// scan one Chebyshev shell R of grid G; per-lane local top-3 accumulate.
__device__ __forceinline__ void scan_shell(
    int R, int sl, int G, int cx, int cy, int cz,
    const int* __restrict__ offs, const float4* __restrict__ spts,
    const int* __restrict__ sidx,
    float qx, float qy, float qz, float sy,
    float& d0, float& d1, float& d2v, int& i0, int& i1, int& i2)
{
  #pragma clang fp contract(off)
  #define DIST_INS(SV, IDV)                                                   \
    { float p0 = qx * SV.x, p1 = qy * SV.y, p2 = qz * SV.z;                   \
      float dt = (p0 + p1) + p2;                                              \
      float S  = sy + SV.w;                                                   \
      float dd = S - 2.0f * dt;                                               \
      ins3(dd, IDV, d0, d1, d2v, i0, i1, i2); }

  #define SCANP()                                                             \
    { int j = js;                                                             \
      for (; j + 4 <= je; j += 4) {                                           \
        float4 s0 = spts[j],     s1 = spts[j + 1];                            \
        float4 s2 = spts[j + 2], s3 = spts[j + 3];                            \
        int id0 = sidx[j],     id1 = sidx[j + 1];                             \
        int id2 = sidx[j + 2], id3 = sidx[j + 3];                             \
        DIST_INS(s0, id0) DIST_INS(s1, id1)                                   \
        DIST_INS(s2, id2) DIST_INS(s3, id3)                                   \
      }                                                                       \
      for (; j < je; ++j) {                                                   \
        float4 s = spts[j]; int id = sidx[j];                                 \
        DIST_INS(s, id)                                                       \
      } }

  if (R == 1) {
    if (sl < 9) {
      int dy = sl % 3 - 1, dz = sl / 3 - 1;
      int yy = cy + dy, zz = cz + dz;
      if (yy >= 0 && yy < G && zz >= 0 && zz < G) {
        int xs = max(cx - 1, 0), xe = min(cx + 1, G - 1);
        int base = (zz * G + yy) * G;
        int js = offs[base + xs], je = offs[base + xe + 1];
        SCANP()
      }
    }
  } else {
    const int twoR1 = 2 * R + 1, inner = 2 * R - 1;
    const int nfz = 2 * twoR1;
    const int nfull = nfz + 2 * inner;
    const int half = inner * inner;
    const int nitems = nfull + 2 * half;
    for (int m = sl; m < nitems; m += 16) {
      int dy, dz, js, je;
      if (m < nfull) {
        if (m < nfz) { dz = (m < twoR1) ? -R : R; dy = (m % twoR1) - R; }
        else { int u = m - nfz; dy = (u < inner) ? -R : R; dz = (u % inner) - (R - 1); }
        int yy = cy + dy, zz = cz + dz;
        if (yy < 0 || yy >= G || zz < 0 || zz >= G) continue;
        int xs = max(cx - R, 0), xe = min(cx + R, G - 1);
        int base = (zz * G + yy) * G;
        js = offs[base + xs]; je = offs[base + xe + 1];
      } else {
        int u = m - nfull;
        int xc = (u < half) ? (cx - R) : (cx + R);
        int r2 = (u < half) ? u : u - half;
        dy = r2 % inner - (R - 1); dz = r2 / inner - (R - 1);
        int yy = cy + dy, zz = cz + dz;
        if (xc < 0 || xc >= G || yy < 0 || yy >= G || zz < 0 || zz >= G) continue;
        int c = (zz * G + yy) * G + xc;
        js = offs[c]; je = offs[c + 1];
      }
      SCANP()
    }
  }
  #undef SCANP
  #undef DIST_INS
}

#define MERGE16(E0, E1, E2, J0, J1, J2)                                       \
  { _Pragma("unroll")                                                         \
    for (int msk = 1; msk < 16; msk <<= 1) {                                  \
      float o0 = __shfl_xor(E0, msk), o1 = __shfl_xor(E1, msk), o2 = __shfl_xor(E2, msk); \
      int   p0 = __shfl_xor(J0, msk), p1 = __shfl_xor(J1, msk), p2 = __shfl_xor(J2, msk); \
      ins3(o0, p0, E0, E1, E2, J0, J1, J2);                                   \
      ins3(o1, p1, E0, E1, E2, J0, J1, J2);                                   \
      ins3(o2, p2, E0, E1, E2, J0, J1, J2);                                   \
    } }

// ---- generic single-grid search: leaves merged top-3 in (e*, j*) ----------
__device__ __forceinline__ void knn_search(
    int sl, float qx, float qy, float qz, float sy, int G,
    const int* __restrict__ offs, const float4* __restrict__ spts,
    const int* __restrict__ sidx,
    float& e0, float& e1, float& e2, int& j0, int& j1, int& j2)
{
  const float cs = 1.0f / (float)G;
  const int cx = cell_clamp(qx, G), cy = cell_clamp(qy, G), cz = cell_clamp(qz, G);
  float d0 = BIGF, d1 = BIGF, d2v = BIGF;
  int i0 = -1, i1 = -1, i2 = -1;
  bool done = false;
  for (int R = 1; R <= G; ++R) {
    if (!done) {
      scan_shell(R, sl, G, cx, cy, cz, offs, spts, sidx,
                 qx, qy, qz, sy, d0, d1, d2v, i0, i1, i2);
      e0 = d0; e1 = d1; e2 = d2v; j0 = i0; j1 = i1; j2 = i2;
      MERGE16(e0, e1, e2, j0, j1, j2)
      float bnd = (float)R * cs;
      done = (e2 <= bnd * bnd - 1e-6f) || (R >= G);
    }
    if (__all(done)) break;
  }
}

// ---- knn0 + inlined build_t (grid G1 over h_pos2 sources); QPB q/block -----
template <int QPB>
__device__ void knn0_bt_body(
    int bid,
    const float4* __restrict__ qspts, const int* __restrict__ qsidx, int Nq,
    int G, const int* __restrict__ offs, const float4* __restrict__ spts, const int* __restrict__ sidx,
    const float* __restrict__ emb1, const float* __restrict__ emb2,
    unsigned short* __restrict__ t_hi, unsigned short* __restrict__ t_lo)
{
  const int sl = threadIdx.x & 15;
  const int qs = bid * QPB + (threadIdx.x >> 4);
  if (qs >= Nq) return;
  float4 qv = qspts[qs];
  const int qorig = qsidx[qs];

  float e0, e1, e2; int j0, j1, j2;
  knn_search(sl, qv.x, qv.y, qv.z, qv.w, G, offs, spts, sidx,
             e0, e1, e2, j0, j1, j2);

  // inlined build_t: every lane holds the merged result post-butterfly.
  float w0 = 1.0f / fmaxf(e0, 1e-16f);
  float w1 = 1.0f / fmaxf(e1, 1e-16f);
  float w2 = 1.0f / fmaxf(e2, 1e-16f);
  float inv = 1.0f / (w0 + w1 + w2);
  w0 *= inv; w1 *= inv; w2 *= inv;
  const float4* e1p = (const float4*)emb1;
  const float4* e2p = (const float4*)emb2;
  #pragma unroll
  for (int k = 0; k < 4; ++k) {
    int c4 = sl + 16 * k;                      // coalesced across the group
    float4 a  = e1p[(size_t)qorig * 64 + c4];
    float4 f0 = e2p[(size_t)j0 * 64 + c4];
    float4 f1 = e2p[(size_t)j1 * 64 + c4];
    float4 f2 = e2p[(size_t)j2 * 64 + c4];
    float4 r;
    r.x = a.x - (w0 * f0.x + w1 * f1.x + w2 * f2.x);
    r.y = a.y - (w0 * f0.y + w1 * f1.y + w2 * f2.y);
    r.z = a.z - (w0 * f0.z + w1 * f1.z + w2 * f2.z);
    r.w = a.w - (w0 * f0.w + w1 * f1.w + w2 * f2.w);
    ushort4 h, l;
    h.x = f2bf(r.x); l.x = f2bf(r.x - bf2f(h.x));
    h.y = f2bf(r.y); l.y = f2bf(r.y - bf2f(h.y));
    h.z = f2bf(r.z); l.z = f2bf(r.z - bf2f(h.z));
    h.w = f2bf(r.w); l.w = f2bf(r.w - bf2f(h.w));
    size_t o = (size_t)qorig * 256 + (size_t)c4 * 4;
    *(ushort4*)&t_hi[o] = h;
    *(ushort4*)&t_lo[o] = l;
  }
}

// ---- knn2: search grid G2 (l_pos1 sources), write (wC, idxC) ---------------
template <int QPB>
__device__ void knn2_body(
    int bid,
    const float4* __restrict__ qspts, const int* __restrict__ qsidx, int Nq,
    int G, const int* __restrict__ offs, const float4* __restrict__ spts, const int* __restrict__ sidx,
    float* __restrict__ wC_out, int* __restrict__ iC_out)
{
  const int sl = threadIdx.x & 15;
  const int qs = bid * QPB + (threadIdx.x >> 4);
  if (qs >= Nq) return;
  float4 qv = qspts[qs];
  const int qorig = qsidx[qs];

  float e0, e1, e2; int j0, j1, j2;
  knn_search(sl, qv.x, qv.y, qv.z, qv.w, G, offs, spts, sidx,
             e0, e1, e2, j0, j1, j2);

  if (sl == 0) {
    float w0 = 1.0f / fmaxf(e0, 1e-16f);
    float w1 = 1.0f / fmaxf(e1, 1e-16f);
    float w2 = 1.0f / fmaxf(e2, 1e-16f);
    float inv = 1.0f / (w0 + w1 + w2);
    wC_out[(size_t)qorig * 3 + 0] = w0 * inv;
    wC_out[(size_t)qorig * 3 + 1] = w1 * inv;
    wC_out[(size_t)qorig * 3 + 2] = w2 * inv;
    iC_out[(size_t)qorig * 3 + 0] = j0;
    iC_out[(size_t)qorig * 3 + 1] = j1;
    iC_out[(size_t)qorig * 3 + 2] = j2;
  }
}

// ---- knn1: search grid (l_pos2 sources), out3 = base3 - interp(feat3) ------
template <int QPB>
__device__ void knn1_body(
    int bid,
    const float4* __restrict__ qspts, const int* __restrict__ qsidx, int Nq, int G,
    const int* __restrict__ offs, const float4* __restrict__ spts, const int* __restrict__ sidx,
    const float* __restrict__ base3, const float* __restrict__ feat3,
    float* __restrict__ out3)
{
  const int sl = threadIdx.x & 15;
  const int qs = bid * QPB + (threadIdx.x >> 4);
  if (qs >= Nq) return;
  float4 qv = qspts[qs];
  const int qorig = qsidx[qs];

  float e0, e1, e2; int j0, j1, j2;
  knn_search(sl, qv.x, qv.y, qv.z, qv.w, G, offs, spts, sidx,
             e0, e1, e2, j0, j1, j2);

  if (sl == 0) {
    float w0 = 1.0f / fmaxf(e0, 1e-16f);
    float w1 = 1.0f / fmaxf(e1, 1e-16f);
    float w2 = 1.0f / fmaxf(e2, 1e-16f);
    float inv = 1.0f / (w0 + w1 + w2);
    w0 *= inv; w1 *= inv; w2 *= inv;
    #pragma unroll
    for (int f = 0; f < 3; ++f) {
      float v = w0 * feat3[(size_t)j0 * 3 + f]
              + w1 * feat3[(size_t)j1 * 3 + f]
              + w2 * feat3[(size_t)j2 * 3 + f];
      out3[(size_t)qorig * 3 + f] = base3[(size_t)qorig * 3 + f] - v;
    }
  }
}

// res[q,:] = sum_k wC[q,k] * diff[idxC[q,k],:]
__device__ void res_gather_body(
    int bid, const float* __restrict__ wC, const int* __restrict__ idxC,
    const float* __restrict__ diff, float* __restrict__ res, int Nq)
{
  int q = bid * 256 + threadIdx.x;
  if (q >= Nq) return;
  float w0 = wC[(size_t)q * 3 + 0], w1 = wC[(size_t)q * 3 + 1], w2 = wC[(size_t)q * 3 + 2];
  int i0 = idxC[(size_t)q * 3 + 0], i1 = idxC[(size_t)q * 3 + 1], i2 = idxC[(size_t)q * 3 + 2];
  #pragma unroll
  for (int f = 0; f < 3; ++f) {
    res[(size_t)q * 3 + f] = w0 * diff[(size_t)i0 * 3 + f]
                           + w1 * diff[(size_t)i1 * 3 + f]
                           + w2 * diff[(size_t)i2 * 3 + f];
  }
}

// ---- critical-path KNN: knn0+bt only (2048 blocks x 128 thr, 8q each) ------
__global__ __launch_bounds__(128) void knn0_kernel(
    const float4* qspts, const int* qsidx, int Nh,
    int G1, const int* offs1, const float4* spts1, const int* sidx1,
    const float* emb1, const float* emb2,
    unsigned short* t_hi, unsigned short* t_lo)
{
  knn0_bt_body<8>(blockIdx.x, qspts, qsidx, Nh, G1, offs1, spts1, sidx1,
                  emb1, emb2, t_hi, t_lo);
}

// ---------------------------------------------------------------------------
// bf16x3-split MFMA GEMM, LDS-FREE (r22): B fragments read directly from the
// L2-resident transposed splits — identical operand values & MFMA order as
// the r12-r21 LDS version (bit-identical output), but no barriers and no
// LDS reservation, so occupancy is register-bound and rider blocks thrive.
//   variant 1 (gemm1): tail = knn2 (nA blocks, 16q) then knn1 (16q)
//   variant 0 (gemm2): tail = res_gather
// ---------------------------------------------------------------------------
__global__ __launch_bounds__(256) void mfma_gemm_kernel(
    const unsigned short* __restrict__ A_hi, const unsigned short* __restrict__ A_lo,
    const unsigned short* __restrict__ BT_hi, const unsigned short* __restrict__ BT_lo,
    const float* __restrict__ bias,
    float* __restrict__ outf,
    unsigned short* __restrict__ out_hi, unsigned short* __restrict__ out_lo,
    int relu, int split_out, int ngemm, int variant, int nA,
    // knn2 args (variant 1)
    const float4* qspts, const int* qsidx, int Nh,
    int G2, const int* offs3, const float4* spts3, const int* sidx3,
    float* wC, int* idxC,
    // knn1 args (variant 1)
    int Nl, const int* offs2, const float4* spts2, const int* sidx2,
    const float* l_y1, const float* l_y2, float* diff,
    // res_gather args (variant 0)
    const float* wCr, const int* idxCr, const float* diffr, float* resout, int NqG)
{
  const int t = threadIdx.x;
  const int d = blockIdx.x;
  if (d >= ngemm) {
    int a = d - ngemm;
    if (variant == 1) {
      if (a < nA)
        knn2_body<16>(a, qspts, qsidx, Nh, G2, offs3, spts3, sidx3, wC, idxC);
      else
        knn1_body<16>(a - nA, spts3, sidx3, Nl, G2, offs2, spts2, sidx2,
                      l_y1, l_y2, diff);
    } else {
      res_gather_body(a, wCr, idxCr, diffr, resout, NqG);
    }
    return;
  }
  const int xcd = d & 7, slot = d >> 3;
  const int lin = xcd * (ngemm >> 3) + slot;
  const int row0 = (lin >> 2) * 64;
  const int col0 = (lin & 3) * 64;

  const int l = t & 63, w = t >> 6;
  const int lr = l & 15;
  const int lk = (l >> 4) << 3;
  const unsigned short* arh = A_hi + (size_t)(row0 + w * 16 + lr) * 256;
  const unsigned short* arl = A_lo + (size_t)(row0 + w * 16 + lr) * 256;
  const unsigned short* br0h = BT_hi + (size_t)(col0 +  0 + lr) * 256;
  const unsigned short* br0l = BT_lo + (size_t)(col0 +  0 + lr) * 256;
  const unsigned short* br1h = BT_hi + (size_t)(col0 + 16 + lr) * 256;
  const unsigned short* br1l = BT_lo + (size_t)(col0 + 16 + lr) * 256;
  const unsigned short* br2h = BT_hi + (size_t)(col0 + 32 + lr) * 256;
  const unsigned short* br2l = BT_lo + (size_t)(col0 + 32 + lr) * 256;
  const unsigned short* br3h = BT_hi + (size_t)(col0 + 48 + lr) * 256;
  const unsigned short* br3l = BT_lo + (size_t)(col0 + 48 + lr) * 256;

  f32x4 acc0 = {0.f,0.f,0.f,0.f}, acc1 = {0.f,0.f,0.f,0.f};
  f32x4 acc2 = {0.f,0.f,0.f,0.f}, acc3 = {0.f,0.f,0.f,0.f};

  #pragma unroll
  for (int k = 0; k < 256; k += 32) {
    int ko = k + lk;
    s16x8 ah = *(const s16x8*)&arh[ko];
    s16x8 al = *(const s16x8*)&arl[ko];
    {
      s16x8 bh = *(const s16x8*)&br0h[ko];
      s16x8 bl = *(const s16x8*)&br0l[ko];
      acc0 = __builtin_amdgcn_mfma_f32_16x16x32_bf16(ah, bh, acc0, 0, 0, 0);
      acc0 = __builtin_amdgcn_mfma_f32_16x16x32_bf16(al, bh, acc0, 0, 0, 0);
      acc0 = __builtin_amdgcn_mfma_f32_16x16x32_bf16(ah, bl, acc0, 0, 0, 0);
    }
    {
      s16x8 bh = *(const s16x8*)&br1h[ko];
      s16x8 bl = *(const s16x8*)&br1l[ko];
      acc1 = __builtin_amdgcn_mfma_f32_16x16x32_bf16(ah, bh, acc1, 0, 0, 0);
      acc1 = __builtin_amdgcn_mfma_f32_16x16x32_bf16(al, bh, acc1, 0, 0, 0);
      acc1 = __builtin_amdgcn_mfma_f32_16x16x32_bf16(ah, bl, acc1, 0, 0, 0);
    }
    {
      s16x8 bh = *(const s16x8*)&br2h[ko];
      s16x8 bl = *(const s16x8*)&br2l[ko];
      acc2 = __builtin_amdgcn_mfma_f32_16x16x32_bf16(ah, bh, acc2, 0, 0, 0);
      acc2 = __builtin_amdgcn_mfma_f32_16x16x32_bf16(al, bh, acc2, 0, 0, 0);
      acc2 = __builtin_amdgcn_mfma_f32_16x16x32_bf16(ah, bl, acc2, 0, 0, 0);
    }
    {
      s16x8 bh = *(const s16x8*)&br3h[ko];
      s16x8 bl = *(const s16x8*)&br3l[ko];
      acc3 = __builtin_amdgcn_mfma_f32_16x16x32_bf16(ah, bh, acc3, 0, 0, 0);
      acc3 = __builtin_amdgcn_mfma_f32_16x16x32_bf16(al, bh, acc3, 0, 0, 0);
      acc3 = __builtin_amdgcn_mfma_f32_16x16x32_bf16(ah, bl, acc3, 0, 0, 0);
    }
  }

  const int orow = row0 + w * 16 + ((l >> 4) << 2);
  #define EPILOG(CT, ACC)                                                     \
    { int col = col0 + CT * 16 + lr;                                          \
      float bb = bias[col];                                                   \
      _Pragma("unroll")                                                       \
      for (int r = 0; r < 4; ++r) {                                           \
        float v = ACC[r] + bb;                                                \
        if (relu) v = fmaxf(v, 0.0f);                                         \
        size_t o = (size_t)(orow + r) * 256 + col;                            \
        if (split_out) {                                                      \
          unsigned short hh = f2bf(v);                                        \
          out_hi[o] = hh; out_lo[o] = f2bf(v - bf2f(hh));                     \
        } else {                                                              \
          outf[o] = v;                                                        \
        }                                                                     \
      } }
  EPILOG(0, acc0)
  EPILOG(1, acc1)
  EPILOG(2, acc2)
  EPILOG(3, acc3)
  #undef EPILOG
}

// ---- grid build ------------------------------------------------------------
__global__ __launch_bounds__(256) void zero_kernel(int* __restrict__ p, int n) {
  int i = blockIdx.x * 256 + threadIdx.x;
  if (i < n) p[i] = 0;
}

// count (blocks 0..159) + weight splits (blocks 160..671)
__global__ __launch_bounds__(256) void count_split_kernel(
    const float* __restrict__ p1, int n1, int g1, int* __restrict__ c1,
    const float* __restrict__ p2, int n2, int g2, int* __restrict__ c2,
    const float* __restrict__ p3, int n3, int g3, int* __restrict__ c3,
    const float* __restrict__ p4, int n4, int g4, int* __restrict__ c4,
    const float* __restrict__ W1, unsigned short* __restrict__ h1T, unsigned short* __restrict__ l1T,
    const float* __restrict__ W2, unsigned short* __restrict__ h2T, unsigned short* __restrict__ l2T)
{
  int b = blockIdx.x;
  if (b >= 160) {
    int sb = b - 160;
    const float* W = (sb < 256) ? W1 : W2;
    unsigned short* hiT = (sb < 256) ? h1T : h2T;
    unsigned short* loT = (sb < 256) ? l1T : l2T;
    int id = (sb & 255) * 256 + threadIdx.x;
    int k = id >> 8, n = id & 255;
    float x = W[id];
    unsigned short h = f2bf(x);
    unsigned short l = f2bf(x - bf2f(h));
    hiT[n * 256 + k] = h;
    loT[n * 256 + k] = l;
    return;
  }
  const float* p; int n, G; int* cnt; int i;
  if (b < 64)       { p = p1; n = n1; G = g1; cnt = c1; i = b * 256 + threadIdx.x; }
  else if (b < 80)  { p = p2; n = n2; G = g2; cnt = c2; i = (b - 64) * 256 + threadIdx.x; }
  else if (b < 96)  { p = p3; n = n3; G = g3; cnt = c3; i = (b - 80) * 256 + threadIdx.x; }
  else              { p = p4; n = n4; G = g4; cnt = c4; i = (b - 96) * 256 + threadIdx.x; }
  if (i >= n) return;
  int cx = cell_clamp(p[3 * i],     G);
  int cy = cell_clamp(p[3 * i + 1], G);
  int cz = cell_clamp(p[3 * i + 2], G);
  atomicAdd(&cnt[(cz * G + cy) * G + cx], 1);
}

__global__ __launch_bounds__(256) void prefix4_kernel(
    const int* __restrict__ c1, int* __restrict__ o1, int* __restrict__ u1, int m1,
    const int* __restrict__ c2, int* __restrict__ o2, int* __restrict__ u2, int m2,
    const int* __restrict__ c3, int* __restrict__ o3, int* __restrict__ u3, int m3,
    const int* __restrict__ c4, int* __restrict__ o4, int* __restrict__ u4, int m4)
{
  const int* cnt; int* offs; int* cur; int M;
  if (blockIdx.x == 0)      { cnt = c1; offs = o1; cur = u1; M = m1; }
  else if (blockIdx.x == 1) { cnt = c2; offs = o2; cur = u2; M = m2; }
  else if (blockIdx.x == 2) { cnt = c3; offs = o3; cur = u3; M = m3; }
  else                      { cnt = c4; offs = o4; cur = u4; M = m4; }
  __shared__ int ps[256];
  const int tid = threadIdx.x;
  const int per = (M + 255) >> 8;
  const int base = tid * per;
  int s = 0;
  for (int j = 0; j < per; ++j) if (base + j < M) s += cnt[base + j];
  ps[tid] = s;
  __syncthreads();
  for (int off = 1; off < 256; off <<= 1) {
    int v = (tid >= off) ? ps[tid - off] : 0;
    __syncthreads();
    ps[tid] += v;
    __syncthreads();
  }
  int run = (tid > 0) ? ps[tid - 1] : 0;
  for (int j = 0; j < per; ++j) {
    if (base + j < M) {
      offs[base + j] = run; cur[base + j] = run;
      run += cnt[base + j];
    }
  }
  if (tid == 255) offs[M] = run;
}

__global__ __launch_bounds__(256) void scatter4_kernel(
    const float* __restrict__ p1, int n1, int g1, int* __restrict__ u1, float4* __restrict__ s1, int* __restrict__ x1,
    const float* __restrict__ p2, int n2, int g2, int* __restrict__ u2, float4* __restrict__ s2, int* __restrict__ x2,
    const float* __restrict__ p3, int n3, int g3, int* __restrict__ u3, float4* __restrict__ s3, int* __restrict__ x3,
    const float* __restrict__ p4, int n4, int g4, int* __restrict__ u4, float4* __restrict__ s4, int* __restrict__ x4)
{
  #pragma clang fp contract(off)
  int b = blockIdx.x;
  const float* p; int n, G; int* cur; float4* spts; int* sidx; int i;
  if (b < 64)       { p = p1; n = n1; G = g1; cur = u1; spts = s1; sidx = x1; i = b * 256 + threadIdx.x; }
  else if (b < 80)  { p = p2; n = n2; G = g2; cur = u2; spts = s2; sidx = x2; i = (b - 64) * 256 + threadIdx.x; }
  else if (b < 96)  { p = p3; n = n3; G = g3; cur = u3; spts = s3; sidx = x3; i = (b - 80) * 256 + threadIdx.x; }
  else              { p = p4; n = n4; G = g4; cur = u4; spts = s4; sidx = x4; i = (b - 96) * 256 + threadIdx.x; }
  if (i >= n) return;
  float x = p[3 * i], y = p[3 * i + 1], z = p[3 * i + 2];
  int cx = cell_clamp(x, G), cy = cell_clamp(y, G), cz = cell_clamp(z, G);
  int c = (cz * G + cy) * G + cx;
  int pos = atomicAdd(&cur[c], 1);
  float sx = (x * x + y * y) + z * z;   // sequential, no contraction
  spts[pos] = make_float4(x, y, z, sx);
  sidx[pos] = i;
}

// ---------------------------------------------------------------------------
// out[r, :] = h2[r, :] @ W3[256,3] + b3 + res[r, :]   (wave per row)
// ---------------------------------------------------------------------------
__global__ __launch_bounds__(256) void final_kernel(
    const float* __restrict__ h2, const float* __restrict__ W3,
    const float* __restrict__ b3, const float* __restrict__ res,
    float* __restrict__ out, int M)
{
  __shared__ float sW3[768];
  const int tid = threadIdx.x;
  for (int i = tid; i < 768; i += 256) sW3[i] = W3[i];
  __syncthreads();

  const int wave = tid >> 6, lane = tid & 63;
  const int r = blockIdx.x * 4 + wave;
  if (r >= M) return;

  float4 h = ((const float4*)h2)[(size_t)r * 64 + lane];
  const int c = lane * 4;
  float a0 = h.x * sW3[(c + 0) * 3 + 0] + h.y * sW3[(c + 1) * 3 + 0]
           + h.z * sW3[(c + 2) * 3 + 0] + h.w * sW3[(c + 3) * 3 + 0];
  float a1 = h.x * sW3[(c + 0) * 3 + 1] + h.y * sW3[(c + 1) * 3 + 1]
           + h.z * sW3[(c + 2) * 3 + 1] + h.w * sW3[(c + 3) * 3 + 1];
  float a2 = h.x * sW3[(c + 0) * 3 + 2] + h.y * sW3[(c + 1) * 3 + 2]
           + h.z * sW3[(c + 2) * 3 + 2] + h.w * sW3[(c + 3) * 3 + 2];

  #pragma unroll
  for (int off = 32; off; off >>= 1) {
    a0 += __shfl_xor(a0, off);
    a1 += __shfl_xor(a1, off);
    a2 += __shfl_xor(a2, off);
  }
  if (lane == 0) {
    out[(size_t)r * 3 + 0] = a0 + b3[0] + res[(size_t)r * 3 + 0];
    out[(size_t)r * 3 + 1] = a1 + b3[1] + res[(size_t)r * 3 + 1];
    out[(size_t)r * 3 + 2] = a2 + b3[2] + res[(size_t)r * 3 + 2];
  }
}

// ---------------------------------------------------------------------------
extern "C" void kernel_launch(void* const* d_in, const int* in_sizes, int n_in,
                              void* d_out, int out_size, void* d_ws, size_t ws_size,
                              hipStream_t stream) {
  (void)in_sizes; (void)n_in; (void)out_size; (void)ws_size;
  const float* emb1   = (const float*)d_in[0];
  const float* l_y1   = (const float*)d_in[1];
  const float* l_pos1 = (const float*)d_in[2];
  const float* h_pos1 = (const float*)d_in[3];
  const float* emb2   = (const float*)d_in[4];
  const float* l_y2   = (const float*)d_in[5];
  const float* l_pos2 = (const float*)d_in[6];
  const float* h_pos2 = (const float*)d_in[7];
  const float* W1     = (const float*)d_in[8];
  const float* b1     = (const float*)d_in[9];
  const float* W2     = (const float*)d_in[10];
  const float* b2     = (const float*)d_in[11];
  const float* W3     = (const float*)d_in[12];
  const float* b3     = (const float*)d_in[13];
  float* out = (float*)d_out;

  const int Nh = 16384, Nl = 4096, H = 256;
  const int G1 = 16, G2 = 10;          // proven r19 config
  const int M1 = G1 * G1 * G1, M2 = G2 * G2 * G2;

  // ---- workspace carve-up (sequential bump allocator, 256B aligned) ----
  char* wsp = (char*)d_ws;
  size_t off = 0;
  auto alloc = [&](size_t bytes) -> void* {
    void* p = wsp + off;
    off += (bytes + 255) & ~(size_t)255;
    return p;
  };
  int*            idxC   = (int*)           alloc((size_t)Nh * 3 * 4);
  float*          wC     = (float*)         alloc((size_t)Nh * 3 * 4);
  unsigned short* t_hi   = (unsigned short*)alloc((size_t)Nh * H * 2);
  unsigned short* t_lo   = (unsigned short*)alloc((size_t)Nh * H * 2);
  unsigned short* h1_hi  = (unsigned short*)alloc((size_t)Nh * H * 2);
  unsigned short* h1_lo  = (unsigned short*)alloc((size_t)Nh * H * 2);
  float*          h2     = (float*)t_hi;    // alias over t_hi+t_lo (t dead)
  unsigned short* w1t_hi = (unsigned short*)alloc((size_t)H * H * 2);
  unsigned short* w1t_lo = (unsigned short*)alloc((size_t)H * H * 2);
  unsigned short* w2t_hi = (unsigned short*)alloc((size_t)H * H * 2);
  unsigned short* w2t_lo = (unsigned short*)alloc((size_t)H * H * 2);
  float*          diff   = (float*)         alloc((size_t)Nl * 3 * 4);
  float*          res    = (float*)         alloc((size_t)Nh * 3 * 4);
  int*            cnts   = (int*)           alloc((size_t)(M1 + M2 + M2 + M1) * 4);
  int* cnt1 = cnts, *cnt2 = cnts + M1, *cnt3 = cnts + M1 + M2, *cnt4 = cnts + M1 + 2 * M2;
  int*            offs1  = (int*)           alloc((size_t)(M1 + 1) * 4);
  int*            cur1   = (int*)           alloc((size_t)M1 * 4);
  int*            offs2  = (int*)           alloc((size_t)(M2 + 1) * 4);
  int*            cur2   = (int*)           alloc((size_t)M2 * 4);
  int*            offs3  = (int*)           alloc((size_t)(M2 + 1) * 4);
  int*            cur3   = (int*)           alloc((size_t)M2 * 4);
  int*            offs4  = (int*)           alloc((size_t)(M1 + 1) * 4);
  int*            cur4   = (int*)           alloc((size_t)M1 * 4);
  float4*         spts1  = (float4*)        alloc((size_t)Nh * 16);
  int*            sidx1  = (int*)           alloc((size_t)Nh * 4);
  float4*         spts2  = (float4*)        alloc((size_t)Nl * 16);
  int*            sidx2  = (int*)           alloc((size_t)Nl * 4);
  float4*         spts3  = (float4*)        alloc((size_t)Nl * 16);
  int*            sidx3  = (int*)           alloc((size_t)Nl * 4);
  float4*         qspts  = (float4*)        alloc((size_t)Nh * 16);   // sorted h_pos1
  int*            qsidx  = (int*)           alloc((size_t)Nh * 4);

  // ---- build grids (3 source + 1 query sort) + weight splits ----
  const int ncnt = M1 + M2 + M2 + M1;
  zero_kernel<<<(ncnt + 255) / 256, 256, 0, stream>>>(cnts, ncnt);
  count_split_kernel<<<672, 256, 0, stream>>>(
      h_pos2, Nh, G1, cnt1,  l_pos2, Nl, G2, cnt2,
      l_pos1, Nl, G2, cnt3,  h_pos1, Nh, G1, cnt4,
      W1, w1t_hi, w1t_lo, W2, w2t_hi, w2t_lo);
  prefix4_kernel<<<4, 256, 0, stream>>>(
      cnt1, offs1, cur1, M1,  cnt2, offs2, cur2, M2,
      cnt3, offs3, cur3, M2,  cnt4, offs4, cur4, M1);
  scatter4_kernel<<<160, 256, 0, stream>>>(
      h_pos2, Nh, G1, cur1, spts1, sidx1,
      l_pos2, Nl, G2, cur2, spts2, sidx2,
      l_pos1, Nl, G2, cur3, spts3, sidx3,
      h_pos1, Nh, G1, cur4, qspts, qsidx);

  // ---- critical path: knn0 + inlined build_t only ----
  knn0_kernel<<<Nh / 8, 128, 0, stream>>>(
      qspts, qsidx, Nh,
      G1, offs1, spts1, sidx1, emb1, emb2, t_hi, t_lo);

  // ---- gemm1 || knn2 || knn1 (LDS-free GEMM; riders get full occupancy) ----
  mfma_gemm_kernel<<<1024 + 1024 + 256, 256, 0, stream>>>(
      t_hi, t_lo, w1t_hi, w1t_lo, b1, nullptr, h1_hi, h1_lo, 1, 1,
      1024, 1, 1024,
      qspts, qsidx, Nh, G2, offs3, spts3, sidx3, wC, idxC,
      Nl, offs2, spts2, sidx2, l_y1, l_y2, diff,
      nullptr, nullptr, nullptr, nullptr, 0);

  // ---- gemm2 || res_gather ----
  mfma_gemm_kernel<<<1024 + 64, 256, 0, stream>>>(
      h1_hi, h1_lo, w2t_hi, w2t_lo, b2, h2, nullptr, nullptr, 1, 0,
      1024, 0, 64,
      nullptr, nullptr, 0, 0, nullptr, nullptr, nullptr, nullptr, nullptr,
      0, nullptr, nullptr, nullptr, nullptr, nullptr, nullptr,
      wC, idxC, diff, res, Nh);

  // ---- final: out = (h2 @ W3 + b3) + res ----
  final_kernel<<<Nh / 4, 256, 0, stream>>>(h2, W3, b3, res, out, Nh);
}

// Round 23
// 109.279 us; speedup vs baseline: 1.5334x; 1.5334x over previous
//
#include <hip/hip_runtime.h>
#include <math.h>

#define BIGF 3.0e38f

typedef short  s16x8 __attribute__((ext_vector_type(8)));
typedef float  f32x4 __attribute__((ext_vector_type(4)));

// bf16 helpers (manual RNE)
__device__ __forceinline__ unsigned short f2bf(float x) {
  unsigned int b = __float_as_uint(x);
  unsigned int r = b + 0x7FFFu + ((b >> 16) & 1u);
  return (unsigned short)(r >> 16);
}
__device__ __forceinline__ float bf2f(unsigned short h) {
  return __uint_as_float(((unsigned int)h) << 16);
}

// ===========================================================================
// r23 = exact revert to round 19 (proven best: 108.8 us).
// Spatial-hash KNN (K=3), 16 lanes per query, row-range shell scan,
// cell-sorted query order, 4-deep batched point loads, 128-thread blocks.
// Selection replicates the np reference's fp32 expansion distance:
//   sx  = (x*x + y*y) + z*z            (sequential, individually rounded)
//   dot = (p0 + p1) + p2, p_k = q_k*s_k
//   d2  = (sy + sx) - 2*dot
// under fp contract(off) (scan_shell-local pragma) — verified rounds 3-6.
// DO NOT TOUCH. Tie-break: lexicographic (d, idx) — scan-order independent.
// Every candidate visited exactly once. Grids G1=16/G2=10.
// Lessons pinned: r20 — GEMM's 33.8KB LDS chokes latency-bound rider blocks;
// r21 — finer grids regress (boundary R=2 escalation); r22 — LDS-free GEMM
// regresses (LDS staging is the L2-latency amortizer, not overhead).
// ===========================================================================

__device__ __forceinline__ int cell_clamp(float v, int G) {
  int c = (int)(v * (float)G);
  return min(G - 1, max(0, c));
}

__device__ __forceinline__ void ins3(float d, int id,
                                     float& d0, float& d1, float& d2,
                                     int& i0, int& i1, int& i2) {
  bool l0 = (d < d0) || (d == d0 && id < i0);
  bool l1 = (d < d1) || (d == d1 && id < i1);
  bool l2 = (d < d2) || (d == d2 && id < i2);
  float nd0 = l0 ? d  : d0;  int ni0 = l0 ? id : i0;
  float nd1 = l0 ? d0 : (l1 ? d  : d1);
  int   ni1 = l0 ? i0 : (l1 ? id : i1);
  float nd2 = l1 ? d1 : (l2 ? d  : d2);
  int   ni2 = l1 ? i1 : (l2 ? id : i2);
  d0 = nd0; d1 = nd1; d2 = nd2; i0 = ni0; i1 = ni1; i2 = ni2;
}

// scan one Chebyshev shell R of grid G; per-lane local top-3 accumulate.
// 4-deep load batching (order-independent thanks to lex tie-break).
__device__ __forceinline__ void scan_shell(
    int R, int sl, int G, int cx, int cy, int cz,
    const int* __restrict__ offs, const float4* __restrict__ spts,
    const int* __restrict__ sidx,
    float qx, float qy, float qz, float sy,
    float& d0, float& d1, float& d2v, int& i0, int& i1, int& i2)
{
  #pragma clang fp contract(off)
  #define DIST_INS(SV, IDV)                                                   \
    { float p0 = qx * SV.x, p1 = qy * SV.y, p2 = qz * SV.z;                   \
      float dt = (p0 + p1) + p2;                                              \
      float S  = sy + SV.w;                                                   \
      float dd = S - 2.0f * dt;                                               \
      ins3(dd, IDV, d0, d1, d2v, i0, i1, i2); }

  #define SCANP()                                                             \
    { int j = js;                                                             \
      for (; j + 4 <= je; j += 4) {                                           \
        float4 s0 = spts[j],     s1 = spts[j + 1];                            \
        float4 s2 = spts[j + 2], s3 = spts[j + 3];                            \
        int id0 = sidx[j],     id1 = sidx[j + 1];                             \
        int id2 = sidx[j + 2], id3 = sidx[j + 3];                             \
        DIST_INS(s0, id0) DIST_INS(s1, id1)                                   \
        DIST_INS(s2, id2) DIST_INS(s3, id3)                                   \
      }                                                                       \
      for (; j < je; ++j) {                                                   \
        float4 s = spts[j]; int id = sidx[j];                                 \
        DIST_INS(s, id)                                                       \
      } }

  if (R == 1) {
    if (sl < 9) {
      int dy = sl % 3 - 1, dz = sl / 3 - 1;
      int yy = cy + dy, zz = cz + dz;
      if (yy >= 0 && yy < G && zz >= 0 && zz < G) {
        int xs = max(cx - 1, 0), xe = min(cx + 1, G - 1);
        int base = (zz * G + yy) * G;
        int js = offs[base + xs], je = offs[base + xe + 1];
        SCANP()
      }
    }
  } else {
    const int twoR1 = 2 * R + 1, inner = 2 * R - 1;
    const int nfz = 2 * twoR1;
    const int nfull = nfz + 2 * inner;
    const int half = inner * inner;
    const int nitems = nfull + 2 * half;
    for (int m = sl; m < nitems; m += 16) {
      int dy, dz, js, je;
      if (m < nfull) {
        if (m < nfz) { dz = (m < twoR1) ? -R : R; dy = (m % twoR1) - R; }
        else { int u = m - nfz; dy = (u < inner) ? -R : R; dz = (u % inner) - (R - 1); }
        int yy = cy + dy, zz = cz + dz;
        if (yy < 0 || yy >= G || zz < 0 || zz >= G) continue;
        int xs = max(cx - R, 0), xe = min(cx + R, G - 1);
        int base = (zz * G + yy) * G;
        js = offs[base + xs]; je = offs[base + xe + 1];
      } else {
        int u = m - nfull;
        int xc = (u < half) ? (cx - R) : (cx + R);
        int r2 = (u < half) ? u : u - half;
        dy = r2 % inner - (R - 1); dz = r2 / inner - (R - 1);
        int yy = cy + dy, zz = cz + dz;
        if (xc < 0 || xc >= G || yy < 0 || yy >= G || zz < 0 || zz >= G) continue;
        int c = (zz * G + yy) * G + xc;
        js = offs[c]; je = offs[c + 1];
      }
      SCANP()
    }
  }
  #undef SCANP
  #undef DIST_INS
}

#define MERGE16(E0, E1, E2, J0, J1, J2)                                       \
  { _Pragma("unroll")                                                         \
    for (int msk = 1; msk < 16; msk <<= 1) {                                  \
      float o0 = __shfl_xor(E0, msk), o1 = __shfl_xor(E1, msk), o2 = __shfl_xor(E2, msk); \
      int   p0 = __shfl_xor(J0, msk), p1 = __shfl_xor(J1, msk), p2 = __shfl_xor(J2, msk); \
      ins3(o0, p0, E0, E1, E2, J0, J1, J2);                                   \
      ins3(o1, p1, E0, E1, E2, J0, J1, J2);                                   \
      ins3(o2, p2, E0, E1, E2, J0, J1, J2);                                   \
    } }

// ---- generic single-grid search: leaves merged top-3 in (e*, j*) ----------
__device__ __forceinline__ void knn_search(
    int sl, float qx, float qy, float qz, float sy, int G,
    const int* __restrict__ offs, const float4* __restrict__ spts,
    const int* __restrict__ sidx,
    float& e0, float& e1, float& e2, int& j0, int& j1, int& j2)
{
  const float cs = 1.0f / (float)G;
  const int cx = cell_clamp(qx, G), cy = cell_clamp(qy, G), cz = cell_clamp(qz, G);
  float d0 = BIGF, d1 = BIGF, d2v = BIGF;
  int i0 = -1, i1 = -1, i2 = -1;
  bool done = false;
  for (int R = 1; R <= G; ++R) {
    if (!done) {
      scan_shell(R, sl, G, cx, cy, cz, offs, spts, sidx,
                 qx, qy, qz, sy, d0, d1, d2v, i0, i1, i2);
      e0 = d0; e1 = d1; e2 = d2v; j0 = i0; j1 = i1; j2 = i2;
      MERGE16(e0, e1, e2, j0, j1, j2)
      float bnd = (float)R * cs;
      done = (e2 <= bnd * bnd - 1e-6f) || (R >= G);
    }
    if (__all(done)) break;
  }
}

// ---- knn0 + inlined build_t (grid G1 over h_pos2 sources); 8 queries/block -
__device__ void knn0_bt_body(
    int bid,
    const float4* __restrict__ qspts, const int* __restrict__ qsidx, int Nq,
    int G, const int* __restrict__ offs, const float4* __restrict__ spts, const int* __restrict__ sidx,
    const float* __restrict__ emb1, const float* __restrict__ emb2,
    unsigned short* __restrict__ t_hi, unsigned short* __restrict__ t_lo)
{
  const int sl = threadIdx.x & 15;
  const int qs = bid * 8 + (threadIdx.x >> 4);
  if (qs >= Nq) return;
  float4 qv = qspts[qs];
  const int qorig = qsidx[qs];

  float e0, e1, e2; int j0, j1, j2;
  knn_search(sl, qv.x, qv.y, qv.z, qv.w, G, offs, spts, sidx,
             e0, e1, e2, j0, j1, j2);

  // inlined build_t: every lane holds the merged result post-butterfly.
  // default contract (same codegen as rounds 12-19's build_t).
  float w0 = 1.0f / fmaxf(e0, 1e-16f);
  float w1 = 1.0f / fmaxf(e1, 1e-16f);
  float w2 = 1.0f / fmaxf(e2, 1e-16f);
  float inv = 1.0f / (w0 + w1 + w2);
  w0 *= inv; w1 *= inv; w2 *= inv;
  const float4* e1p = (const float4*)emb1;
  const float4* e2p = (const float4*)emb2;
  #pragma unroll
  for (int k = 0; k < 4; ++k) {
    int c4 = sl + 16 * k;                      // coalesced across the group
    float4 a  = e1p[(size_t)qorig * 64 + c4];
    float4 f0 = e2p[(size_t)j0 * 64 + c4];
    float4 f1 = e2p[(size_t)j1 * 64 + c4];
    float4 f2 = e2p[(size_t)j2 * 64 + c4];
    float4 r;
    r.x = a.x - (w0 * f0.x + w1 * f1.x + w2 * f2.x);
    r.y = a.y - (w0 * f0.y + w1 * f1.y + w2 * f2.y);
    r.z = a.z - (w0 * f0.z + w1 * f1.z + w2 * f2.z);
    r.w = a.w - (w0 * f0.w + w1 * f1.w + w2 * f2.w);
    ushort4 h, l;
    h.x = f2bf(r.x); l.x = f2bf(r.x - bf2f(h.x));
    h.y = f2bf(r.y); l.y = f2bf(r.y - bf2f(h.y));
    h.z = f2bf(r.z); l.z = f2bf(r.z - bf2f(h.z));
    h.w = f2bf(r.w); l.w = f2bf(r.w - bf2f(h.w));
    size_t o = (size_t)qorig * 256 + (size_t)c4 * 4;
    *(ushort4*)&t_hi[o] = h;
    *(ushort4*)&t_lo[o] = l;
  }
}

// ---- knn2: search grid G2 (l_pos1 sources), write (wC, idxC); 8 q/block ----
__device__ void knn2_body(
    int bid,
    const float4* __restrict__ qspts, const int* __restrict__ qsidx, int Nq,
    int G, const int* __restrict__ offs, const float4* __restrict__ spts, const int* __restrict__ sidx,
    float* __restrict__ wC_out, int* __restrict__ iC_out)
{
  const int sl = threadIdx.x & 15;
  const int qs = bid * 8 + (threadIdx.x >> 4);
  if (qs >= Nq) return;
  float4 qv = qspts[qs];
  const int qorig = qsidx[qs];

  float e0, e1, e2; int j0, j1, j2;
  knn_search(sl, qv.x, qv.y, qv.z, qv.w, G, offs, spts, sidx,
             e0, e1, e2, j0, j1, j2);

  if (sl == 0) {
    float w0 = 1.0f / fmaxf(e0, 1e-16f);
    float w1 = 1.0f / fmaxf(e1, 1e-16f);
    float w2 = 1.0f / fmaxf(e2, 1e-16f);
    float inv = 1.0f / (w0 + w1 + w2);
    wC_out[(size_t)qorig * 3 + 0] = w0 * inv;
    wC_out[(size_t)qorig * 3 + 1] = w1 * inv;
    wC_out[(size_t)qorig * 3 + 2] = w2 * inv;
    iC_out[(size_t)qorig * 3 + 0] = j0;
    iC_out[(size_t)qorig * 3 + 1] = j1;
    iC_out[(size_t)qorig * 3 + 2] = j2;
  }
}

// ---- knn1: search grid (l_pos2 sources), out3 = base3 - interp(feat3) ------
__device__ void knn1_body(
    int bid,
    const float4* __restrict__ qspts, const int* __restrict__ qsidx, int Nq, int G,
    const int* __restrict__ offs, const float4* __restrict__ spts, const int* __restrict__ sidx,
    const float* __restrict__ base3, const float* __restrict__ feat3,
    float* __restrict__ out3)
{
  const int sl = threadIdx.x & 15;
  const int qs = bid * 8 + (threadIdx.x >> 4);
  if (qs >= Nq) return;
  float4 qv = qspts[qs];
  const int qorig = qsidx[qs];

  float e0, e1, e2; int j0, j1, j2;
  knn_search(sl, qv.x, qv.y, qv.z, qv.w, G, offs, spts, sidx,
             e0, e1, e2, j0, j1, j2);

  if (sl == 0) {
    float w0 = 1.0f / fmaxf(e0, 1e-16f);
    float w1 = 1.0f / fmaxf(e1, 1e-16f);
    float w2 = 1.0f / fmaxf(e2, 1e-16f);
    float inv = 1.0f / (w0 + w1 + w2);
    w0 *= inv; w1 *= inv; w2 *= inv;
    #pragma unroll
    for (int f = 0; f < 3; ++f) {
      float v = w0 * feat3[(size_t)j0 * 3 + f]
              + w1 * feat3[(size_t)j1 * 3 + f]
              + w2 * feat3[(size_t)j2 * 3 + f];
      out3[(size_t)qorig * 3 + f] = base3[(size_t)qorig * 3 + f] - v;
    }
  }
}

// res[q,:] = sum_k wC[q,k] * diff[idxC[q,k],:]
__device__ void res_gather_body(
    int bid, const float* __restrict__ wC, const int* __restrict__ idxC,
    const float* __restrict__ diff, float* __restrict__ res, int Nq)
{
  int q = bid * 256 + threadIdx.x;
  if (q >= Nq) return;
  float w0 = wC[(size_t)q * 3 + 0], w1 = wC[(size_t)q * 3 + 1], w2 = wC[(size_t)q * 3 + 2];
  int i0 = idxC[(size_t)q * 3 + 0], i1 = idxC[(size_t)q * 3 + 1], i2 = idxC[(size_t)q * 3 + 2];
  #pragma unroll
  for (int f = 0; f < 3; ++f) {
    res[(size_t)q * 3 + f] = w0 * diff[(size_t)i0 * 3 + f]
                           + w1 * diff[(size_t)i1 * 3 + f]
                           + w2 * diff[(size_t)i2 * 3 + f];
  }
}

// ---- fused KNN dispatch, 128-thread blocks (8 queries each) -----------------
// 4608 blocks = 512 groups x {4 knn0+bt, 4 knn2, 1 knn1}
__global__ __launch_bounds__(128) void knn_all_kernel(
    const float4* qspts, const int* qsidx, int Nh,
    int G1, const int* offs1, const float4* spts1, const int* sidx1,
    const float* emb1, const float* emb2,
    unsigned short* t_hi, unsigned short* t_lo,
    int G2, const int* offs3, const float4* spts3, const int* sidx3,
    float* wC, int* idxC,
    int Nl, const int* offs2, const float4* spts2, const int* sidx2,
    const float* l_y1, const float* l_y2, float* diff)
{
  int g = blockIdx.x / 9, r = blockIdx.x % 9;
  if (r < 4)
    knn0_bt_body(g * 4 + r, qspts, qsidx, Nh, G1, offs1, spts1, sidx1,
                 emb1, emb2, t_hi, t_lo);
  else if (r < 8)
    knn2_body(g * 4 + (r - 4), qspts, qsidx, Nh, G2, offs3, spts3, sidx3,
              wC, idxC);
  else
    knn1_body(g, spts3, sidx3, Nl, G2, offs2, spts2, sidx2,
              l_y1, l_y2, diff);
}

// ---- grid build ------------------------------------------------------------
__global__ __launch_bounds__(256) void zero_kernel(int* __restrict__ p, int n) {
  int i = blockIdx.x * 256 + threadIdx.x;
  if (i < n) p[i] = 0;
}

// count (blocks 0..159) + weight splits (blocks 160..671)
__global__ __launch_bounds__(256) void count_split_kernel(
    const float* __restrict__ p1, int n1, int g1, int* __restrict__ c1,
    const float* __restrict__ p2, int n2, int g2, int* __restrict__ c2,
    const float* __restrict__ p3, int n3, int g3, int* __restrict__ c3,
    const float* __restrict__ p4, int n4, int g4, int* __restrict__ c4,
    const float* __restrict__ W1, unsigned short* __restrict__ h1T, unsigned short* __restrict__ l1T,
    const float* __restrict__ W2, unsigned short* __restrict__ h2T, unsigned short* __restrict__ l2T)
{
  int b = blockIdx.x;
  if (b >= 160) {
    int sb = b - 160;
    const float* W = (sb < 256) ? W1 : W2;
    unsigned short* hiT = (sb < 256) ? h1T : h2T;
    unsigned short* loT = (sb < 256) ? l1T : l2T;
    int id = (sb & 255) * 256 + threadIdx.x;
    int k = id >> 8, n = id & 255;
    float x = W[id];
    unsigned short h = f2bf(x);
    unsigned short l = f2bf(x - bf2f(h));
    hiT[n * 256 + k] = h;
    loT[n * 256 + k] = l;
    return;
  }
  const float* p; int n, G; int* cnt; int i;
  if (b < 64)       { p = p1; n = n1; G = g1; cnt = c1; i = b * 256 + threadIdx.x; }
  else if (b < 80)  { p = p2; n = n2; G = g2; cnt = c2; i = (b - 64) * 256 + threadIdx.x; }
  else if (b < 96)  { p = p3; n = n3; G = g3; cnt = c3; i = (b - 80) * 256 + threadIdx.x; }
  else              { p = p4; n = n4; G = g4; cnt = c4; i = (b - 96) * 256 + threadIdx.x; }
  if (i >= n) return;
  int cx = cell_clamp(p[3 * i],     G);
  int cy = cell_clamp(p[3 * i + 1], G);
  int cz = cell_clamp(p[3 * i + 2], G);
  atomicAdd(&cnt[(cz * G + cy) * G + cx], 1);
}

__global__ __launch_bounds__(256) void prefix4_kernel(
    const int* __restrict__ c1, int* __restrict__ o1, int* __restrict__ u1, int m1,
    const int* __restrict__ c2, int* __restrict__ o2, int* __restrict__ u2, int m2,
    const int* __restrict__ c3, int* __restrict__ o3, int* __restrict__ u3, int m3,
    const int* __restrict__ c4, int* __restrict__ o4, int* __restrict__ u4, int m4)
{
  const int* cnt; int* offs; int* cur; int M;
  if (blockIdx.x == 0)      { cnt = c1; offs = o1; cur = u1; M = m1; }
  else if (blockIdx.x == 1) { cnt = c2; offs = o2; cur = u2; M = m2; }
  else if (blockIdx.x == 2) { cnt = c3; offs = o3; cur = u3; M = m3; }
  else                      { cnt = c4; offs = o4; cur = u4; M = m4; }
  __shared__ int ps[256];
  const int tid = threadIdx.x;
  const int per = (M + 255) >> 8;
  const int base = tid * per;
  int s = 0;
  for (int j = 0; j < per; ++j) if (base + j < M) s += cnt[base + j];
  ps[tid] = s;
  __syncthreads();
  for (int off = 1; off < 256; off <<= 1) {
    int v = (tid >= off) ? ps[tid - off] : 0;
    __syncthreads();
    ps[tid] += v;
    __syncthreads();
  }
  int run = (tid > 0) ? ps[tid - 1] : 0;
  for (int j = 0; j < per; ++j) {
    if (base + j < M) {
      offs[base + j] = run; cur[base + j] = run;
      run += cnt[base + j];
    }
  }
  if (tid == 255) offs[M] = run;
}

__global__ __launch_bounds__(256) void scatter4_kernel(
    const float* __restrict__ p1, int n1, int g1, int* __restrict__ u1, float4* __restrict__ s1, int* __restrict__ x1,
    const float* __restrict__ p2, int n2, int g2, int* __restrict__ u2, float4* __restrict__ s2, int* __restrict__ x2,
    const float* __restrict__ p3, int n3, int g3, int* __restrict__ u3, float4* __restrict__ s3, int* __restrict__ x3,
    const float* __restrict__ p4, int n4, int g4, int* __restrict__ u4, float4* __restrict__ s4, int* __restrict__ x4)
{
  #pragma clang fp contract(off)
  int b = blockIdx.x;
  const float* p; int n, G; int* cur; float4* spts; int* sidx; int i;
  if (b < 64)       { p = p1; n = n1; G = g1; cur = u1; spts = s1; sidx = x1; i = b * 256 + threadIdx.x; }
  else if (b < 80)  { p = p2; n = n2; G = g2; cur = u2; spts = s2; sidx = x2; i = (b - 64) * 256 + threadIdx.x; }
  else if (b < 96)  { p = p3; n = n3; G = g3; cur = u3; spts = s3; sidx = x3; i = (b - 80) * 256 + threadIdx.x; }
  else              { p = p4; n = n4; G = g4; cur = u4; spts = s4; sidx = x4; i = (b - 96) * 256 + threadIdx.x; }
  if (i >= n) return;
  float x = p[3 * i], y = p[3 * i + 1], z = p[3 * i + 2];
  int cx = cell_clamp(x, G), cy = cell_clamp(y, G), cz = cell_clamp(z, G);
  int c = (cz * G + cy) * G + cx;
  int pos = atomicAdd(&cur[c], 1);
  float sx = (x * x + y * y) + z * z;   // sequential, no contraction
  spts[pos] = make_float4(x, y, z, sx);
  sidx[pos] = i;
}

// ---------------------------------------------------------------------------
// bf16x3-split MFMA GEMM (verified round 12 — absmax 0.0625).
// Blocks [0, ngemm) do GEMM; blocks [ngemm, ...) do res_gather.
// ---------------------------------------------------------------------------
__global__ __launch_bounds__(256) void mfma_gemm_kernel(
    const unsigned short* __restrict__ A_hi, const unsigned short* __restrict__ A_lo,
    const unsigned short* __restrict__ BT_hi, const unsigned short* __restrict__ BT_lo,
    const float* __restrict__ bias,
    float* __restrict__ outf,
    unsigned short* __restrict__ out_hi, unsigned short* __restrict__ out_lo,
    int relu, int split_out, int ngemm,
    const float* __restrict__ wC, const int* __restrict__ idxC,
    const float* __restrict__ diff, float* __restrict__ resout, int NqG)
{
  __shared__ unsigned short Bs_hi[64][132];
  __shared__ unsigned short Bs_lo[64][132];
  const int t = threadIdx.x;
  const int d = blockIdx.x;
  if (d >= ngemm) {
    res_gather_body(d - ngemm, wC, idxC, diff, resout, NqG);
    return;
  }
  const int xcd = d & 7, slot = d >> 3;
  const int lin = xcd * (ngemm >> 3) + slot;
  const int row0 = (lin >> 2) * 64;
  const int col0 = (lin & 3) * 64;

  const int l = t & 63, w = t >> 6;
  const int lr = l & 15;
  const int lk = (l >> 4) << 3;
  const unsigned short* arh = A_hi + (size_t)(row0 + w * 16 + lr) * 256;
  const unsigned short* arl = A_lo + (size_t)(row0 + w * 16 + lr) * 256;

  const int sc = t >> 2;
  const int sk = (t & 3) << 5;

  f32x4 acc0 = {0.f,0.f,0.f,0.f}, acc1 = {0.f,0.f,0.f,0.f};
  f32x4 acc2 = {0.f,0.f,0.f,0.f}, acc3 = {0.f,0.f,0.f,0.f};

  #define KSTEP(CT, ACC)                                                      \
    { s16x8 bh = *(const s16x8*)&Bs_hi[CT * 16 + lr][kc + lk];                \
      s16x8 bl = *(const s16x8*)&Bs_lo[CT * 16 + lr][kc + lk];                \
      ACC = __builtin_amdgcn_mfma_f32_16x16x32_bf16(ah, bh, ACC, 0, 0, 0);    \
      ACC = __builtin_amdgcn_mfma_f32_16x16x32_bf16(al, bh, ACC, 0, 0, 0);    \
      ACC = __builtin_amdgcn_mfma_f32_16x16x32_bf16(ah, bl, ACC, 0, 0, 0); }

  for (int half = 0; half < 2; ++half) {
    if (half) __syncthreads();
    {
      const int4* sh = (const int4*)&BT_hi[(size_t)(col0 + sc) * 256 + half * 128 + sk];
      const int4* slo = (const int4*)&BT_lo[(size_t)(col0 + sc) * 256 + half * 128 + sk];
      int4* dh = (int4*)&Bs_hi[sc][sk];
      int4* dl = (int4*)&Bs_lo[sc][sk];
      #pragma unroll
      for (int i = 0; i < 4; ++i) { dh[i] = sh[i]; dl[i] = slo[i]; }
    }
    __syncthreads();
    const int kbase = half * 128;
    #pragma unroll
    for (int kc = 0; kc < 128; kc += 32) {
      s16x8 ah = *(const s16x8*)&arh[kbase + kc + lk];
      s16x8 al = *(const s16x8*)&arl[kbase + kc + lk];
      KSTEP(0, acc0)
      KSTEP(1, acc1)
      KSTEP(2, acc2)
      KSTEP(3, acc3)
    }
  }
  #undef KSTEP

  const int orow = row0 + w * 16 + ((l >> 4) << 2);
  #define EPILOG(CT, ACC)                                                     \
    { int col = col0 + CT * 16 + lr;                                          \
      float bb = bias[col];                                                   \
      _Pragma("unroll")                                                       \
      for (int r = 0; r < 4; ++r) {                                           \
        float v = ACC[r] + bb;                                                \
        if (relu) v = fmaxf(v, 0.0f);                                         \
        size_t o = (size_t)(orow + r) * 256 + col;                            \
        if (split_out) {                                                      \
          unsigned short hh = f2bf(v);                                        \
          out_hi[o] = hh; out_lo[o] = f2bf(v - bf2f(hh));                     \
        } else {                                                              \
          outf[o] = v;                                                        \
        }                                                                     \
      } }
  EPILOG(0, acc0)
  EPILOG(1, acc1)
  EPILOG(2, acc2)
  EPILOG(3, acc3)
  #undef EPILOG
}

// ---------------------------------------------------------------------------
// out[r, :] = h2[r, :] @ W3[256,3] + b3 + res[r, :]   (wave per row)
// ---------------------------------------------------------------------------
__global__ __launch_bounds__(256) void final_kernel(
    const float* __restrict__ h2, const float* __restrict__ W3,
    const float* __restrict__ b3, const float* __restrict__ res,
    float* __restrict__ out, int M)
{
  __shared__ float sW3[768];
  const int tid = threadIdx.x;
  for (int i = tid; i < 768; i += 256) sW3[i] = W3[i];
  __syncthreads();

  const int wave = tid >> 6, lane = tid & 63;
  const int r = blockIdx.x * 4 + wave;
  if (r >= M) return;

  float4 h = ((const float4*)h2)[(size_t)r * 64 + lane];
  const int c = lane * 4;
  float a0 = h.x * sW3[(c + 0) * 3 + 0] + h.y * sW3[(c + 1) * 3 + 0]
           + h.z * sW3[(c + 2) * 3 + 0] + h.w * sW3[(c + 3) * 3 + 0];
  float a1 = h.x * sW3[(c + 0) * 3 + 1] + h.y * sW3[(c + 1) * 3 + 1]
           + h.z * sW3[(c + 2) * 3 + 1] + h.w * sW3[(c + 3) * 3 + 1];
  float a2 = h.x * sW3[(c + 0) * 3 + 2] + h.y * sW3[(c + 1) * 3 + 2]
           + h.z * sW3[(c + 2) * 3 + 2] + h.w * sW3[(c + 3) * 3 + 2];

  #pragma unroll
  for (int off = 32; off; off >>= 1) {
    a0 += __shfl_xor(a0, off);
    a1 += __shfl_xor(a1, off);
    a2 += __shfl_xor(a2, off);
  }
  if (lane == 0) {
    out[(size_t)r * 3 + 0] = a0 + b3[0] + res[(size_t)r * 3 + 0];
    out[(size_t)r * 3 + 1] = a1 + b3[1] + res[(size_t)r * 3 + 1];
    out[(size_t)r * 3 + 2] = a2 + b3[2] + res[(size_t)r * 3 + 2];
  }
}

// ---------------------------------------------------------------------------
extern "C" void kernel_launch(void* const* d_in, const int* in_sizes, int n_in,
                              void* d_out, int out_size, void* d_ws, size_t ws_size,
                              hipStream_t stream) {
  (void)in_sizes; (void)n_in; (void)out_size; (void)ws_size;
  const float* emb1   = (const float*)d_in[0];
  const float* l_y1   = (const float*)d_in[1];
  const float* l_pos1 = (const float*)d_in[2];
  const float* h_pos1 = (const float*)d_in[3];
  const float* emb2   = (const float*)d_in[4];
  const float* l_y2   = (const float*)d_in[5];
  const float* l_pos2 = (const float*)d_in[6];
  const float* h_pos2 = (const float*)d_in[7];
  const float* W1     = (const float*)d_in[8];
  const float* b1     = (const float*)d_in[9];
  const float* W2     = (const float*)d_in[10];
  const float* b2     = (const float*)d_in[11];
  const float* W3     = (const float*)d_in[12];
  const float* b3     = (const float*)d_in[13];
  float* out = (float*)d_out;

  const int Nh = 16384, Nl = 4096, H = 256;
  const int G1 = 16, G2 = 10;
  const int M1 = G1 * G1 * G1, M2 = G2 * G2 * G2;

  // ---- workspace carve-up (sequential bump allocator, 256B aligned) ----
  char* wsp = (char*)d_ws;
  size_t off = 0;
  auto alloc = [&](size_t bytes) -> void* {
    void* p = wsp + off;
    off += (bytes + 255) & ~(size_t)255;
    return p;
  };
  int*            idxC   = (int*)           alloc((size_t)Nh * 3 * 4);
  float*          wC     = (float*)         alloc((size_t)Nh * 3 * 4);
  unsigned short* t_hi   = (unsigned short*)alloc((size_t)Nh * H * 2);
  unsigned short* t_lo   = (unsigned short*)alloc((size_t)Nh * H * 2);
  unsigned short* h1_hi  = (unsigned short*)alloc((size_t)Nh * H * 2);
  unsigned short* h1_lo  = (unsigned short*)alloc((size_t)Nh * H * 2);
  float*          h2     = (float*)t_hi;    // alias over t_hi+t_lo (t dead)
  unsigned short* w1t_hi = (unsigned short*)alloc((size_t)H * H * 2);
  unsigned short* w1t_lo = (unsigned short*)alloc((size_t)H * H * 2);
  unsigned short* w2t_hi = (unsigned short*)alloc((size_t)H * H * 2);
  unsigned short* w2t_lo = (unsigned short*)alloc((size_t)H * H * 2);
  float*          diff   = (float*)         alloc((size_t)Nl * 3 * 4);
  float*          res    = (float*)         alloc((size_t)Nh * 3 * 4);
  int*            cnts   = (int*)           alloc((size_t)(M1 + M2 + M2 + M1) * 4);
  int* cnt1 = cnts, *cnt2 = cnts + M1, *cnt3 = cnts + M1 + M2, *cnt4 = cnts + M1 + 2 * M2;
  int*            offs1  = (int*)           alloc((size_t)(M1 + 1) * 4);
  int*            cur1   = (int*)           alloc((size_t)M1 * 4);
  int*            offs2  = (int*)           alloc((size_t)(M2 + 1) * 4);
  int*            cur2   = (int*)           alloc((size_t)M2 * 4);
  int*            offs3  = (int*)           alloc((size_t)(M2 + 1) * 4);
  int*            cur3   = (int*)           alloc((size_t)M2 * 4);
  int*            offs4  = (int*)           alloc((size_t)(M1 + 1) * 4);
  int*            cur4   = (int*)           alloc((size_t)M1 * 4);
  float4*         spts1  = (float4*)        alloc((size_t)Nh * 16);
  int*            sidx1  = (int*)           alloc((size_t)Nh * 4);
  float4*         spts2  = (float4*)        alloc((size_t)Nl * 16);
  int*            sidx2  = (int*)           alloc((size_t)Nl * 4);
  float4*         spts3  = (float4*)        alloc((size_t)Nl * 16);
  int*            sidx3  = (int*)           alloc((size_t)Nl * 4);
  float4*         qspts  = (float4*)        alloc((size_t)Nh * 16);   // sorted h_pos1
  int*            qsidx  = (int*)           alloc((size_t)Nh * 4);

  // ---- build grids (3 source + 1 query sort) + weight splits ----
  const int ncnt = M1 + M2 + M2 + M1;
  zero_kernel<<<(ncnt + 255) / 256, 256, 0, stream>>>(cnts, ncnt);
  count_split_kernel<<<672, 256, 0, stream>>>(
      h_pos2, Nh, G1, cnt1,  l_pos2, Nl, G2, cnt2,
      l_pos1, Nl, G2, cnt3,  h_pos1, Nh, G1, cnt4,
      W1, w1t_hi, w1t_lo, W2, w2t_hi, w2t_lo);
  prefix4_kernel<<<4, 256, 0, stream>>>(
      cnt1, offs1, cur1, M1,  cnt2, offs2, cur2, M2,
      cnt3, offs3, cur3, M2,  cnt4, offs4, cur4, M1);
  scatter4_kernel<<<160, 256, 0, stream>>>(
      h_pos2, Nh, G1, cur1, spts1, sidx1,
      l_pos2, Nl, G2, cur2, spts2, sidx2,
      l_pos1, Nl, G2, cur3, spts3, sidx3,
      h_pos1, Nh, G1, cur4, qspts, qsidx);

  // ---- all KNN work in one dispatch (128-thread blocks) ----
  knn_all_kernel<<<4608, 128, 0, stream>>>(
      qspts, qsidx, Nh,
      G1, offs1, spts1, sidx1, emb1, emb2, t_hi, t_lo,
      G2, offs3, spts3, sidx3, wC, idxC,
      Nl, offs2, spts2, sidx2, l_y1, l_y2, diff);

  // ---- gemm1 (+ res_gather riding along) ----
  mfma_gemm_kernel<<<1024 + 64, 256, 0, stream>>>(
      t_hi, t_lo, w1t_hi, w1t_lo, b1, nullptr, h1_hi, h1_lo, 1, 1, 1024,
      wC, idxC, diff, res, Nh);
  // ---- gemm2 ----
  mfma_gemm_kernel<<<1024, 256, 0, stream>>>(
      h1_hi, h1_lo, w2t_hi, w2t_lo, b2, h2, nullptr, nullptr, 1, 0, 1024,
      nullptr, nullptr, nullptr, nullptr, 0);

  // ---- final: out = (h2 @ W3 + b3) + res ----
  final_kernel<<<Nh / 4, 256, 0, stream>>>(h2, W3, b3, res, out, Nh);
}